// Round 4
// baseline (357.619 us; speedup 1.0000x reference)
//
#include <hip/hip_runtime.h>
#include <hip/hip_bf16.h>
#include <math.h>

#define TT 2048
#define BB 8
#define DD 128
#define HH 4
#define BT (BB*TT)
#define BH (BB*HH)
#define SCALE 0.1767766952966369f
#define S2LOG (SCALE * 1.4426950408889634f)   // scale * log2(e)

typedef __attribute__((ext_vector_type(8))) short short8;
typedef __attribute__((ext_vector_type(4))) short short4v;
typedef __attribute__((ext_vector_type(4))) float f32x4;
typedef __hip_bfloat16 bf16;

#define MFMA16(a,b,c) __builtin_amdgcn_mfma_f32_16x16x32_bf16(a,b,c,0,0,0)

static __device__ inline short8 ldg8(const bf16* p) {
  return *reinterpret_cast<const short8*>(p);
}
static __device__ inline short4v ldg4(const bf16* p) {
  return *reinterpret_cast<const short4v*>(p);
}
static __device__ inline short f2bs(float x) {
  bf16 h = __float2bfloat16(x);
  return *reinterpret_cast<short*>(&h);
}
// load 8 contiguous f32 from global, convert to bf16 A/B-fragment
static __device__ inline short8 ldcvt8(const float* p) {
  f32x4 f0 = *reinterpret_cast<const f32x4*>(p);
  f32x4 f1 = *reinterpret_cast<const f32x4*>(p + 4);
  short8 r;
  #pragma unroll
  for (int i = 0; i < 4; ++i) { r[i] = f2bs(f0[i]); r[4+i] = f2bs(f1[i]); }
  return r;
}

// ---------------- Kernel 1: MFMA projections ----------------
// q,k staged in LDS and written out as fully-contiguous short8 runs
// (previously 48 scalar 2B stores per lane).
__global__ __launch_bounds__(256) void proj_kernel(
    const float* __restrict__ lob, const float* __restrict__ hawkes,
    const float* __restrict__ Wp, const float* __restrict__ bp,
    const float* __restrict__ Win, const float* __restrict__ binp,
    bf16* __restrict__ qg, bf16* __restrict__ kg, bf16* __restrict__ vtg) {
  __shared__ bf16 hT[32*136];   // h tile; reused as q staging after ah read
  __shared__ bf16 sK[32*136];   // k staging
  __shared__ bf16 vT[128*40];   // v^T staging
  int tid = threadIdx.x;
  int wave = tid >> 6, lane = tid & 63;
  int lr = lane & 15, lq = lane >> 4;
  int r0 = blockIdx.x * 32;
  int b  = r0 >> 11, t0 = r0 & 2047;
  f32x4 z = {0.f,0.f,0.f,0.f};

  short8 alob[2][4], ahk[2];
  #pragma unroll
  for (int mt = 0; mt < 2; ++mt) {
    const float* lp = lob + (size_t)(r0 + mt*16 + lr)*128;
    #pragma unroll
    for (int kt = 0; kt < 4; ++kt) alob[mt][kt] = ldcvt8(lp + kt*32 + lq*8);
    ahk[mt] = ldcvt8(hawkes + (size_t)(r0 + mt*16 + lr)*32 + lq*8);
  }

  for (int nt = wave; nt < 8; nt += 4) {
    int cn = nt*16;
    short8 bfrag = ldcvt8(Wp + (size_t)(cn + lr)*32 + lq*8);
    float bias = bp[cn + lr];
    #pragma unroll
    for (int mt = 0; mt < 2; ++mt) {
      f32x4 c = MFMA16(ahk[mt], bfrag, z);
      #pragma unroll
      for (int r = 0; r < 4; ++r)
        hT[(mt*16 + lq*4 + r)*136 + cn + lr] = __float2bfloat16(c[r] + bias);
    }
  }
  __syncthreads();

  short8 ah[2][4];
  #pragma unroll
  for (int mt = 0; mt < 2; ++mt)
    #pragma unroll
    for (int kt = 0; kt < 4; ++kt)
      ah[mt][kt] = *reinterpret_cast<const short8*>(&hT[(mt*16 + lr)*136 + kt*32 + lq*8]);
  __syncthreads();   // hT free -> reuse as q staging

  for (int nt = wave; nt < 24; nt += 4) {
    int which = nt >> 3;
    int c = (nt & 7)*16 + lr;
    const float* wrow = Win + (size_t)(which*128 + c)*128;
    float bias = binp[which*128 + c];
    f32x4 acc0 = z, acc1 = z;
    #pragma unroll
    for (int kt = 0; kt < 4; ++kt) {
      short8 bfrag = ldcvt8(wrow + kt*32 + lq*8);
      if (which == 0) {
        acc0 = MFMA16(alob[0][kt], bfrag, acc0);
        acc1 = MFMA16(alob[1][kt], bfrag, acc1);
      } else {
        acc0 = MFMA16(ah[0][kt], bfrag, acc0);
        acc1 = MFMA16(ah[1][kt], bfrag, acc1);
      }
    }
    #pragma unroll
    for (int mt = 0; mt < 2; ++mt) {
      f32x4 acc = mt ? acc1 : acc0;
      #pragma unroll
      for (int r = 0; r < 4; ++r) {
        int row = mt*16 + lq*4 + r;
        float val = acc[r] + bias;
        if (which == 0)      hT[row*136 + c] = __float2bfloat16(val);
        else if (which == 1) sK[row*136 + c] = __float2bfloat16(val);
        else                 vT[c*40 + row]  = __float2bfloat16(val);
      }
    }
  }
  __syncthreads();

  // q,k writeout: 256 threads x 32B, fully contiguous 4KB per head
  {
    int head = tid >> 6, tt = (tid >> 1) & 31, half = tid & 1;
    const bf16* sq = &hT[tt*136 + head*32 + half*16];
    const bf16* sk = &sK[tt*136 + head*32 + half*16];
    bf16* qdst = qg + ((size_t)(b*HH + head)*TT + t0 + tt)*32 + half*16;
    bf16* kdst = kg + ((size_t)(b*HH + head)*TT + t0 + tt)*32 + half*16;
    *reinterpret_cast<short8*>(qdst)     = *reinterpret_cast<const short8*>(sq);
    *reinterpret_cast<short8*>(qdst + 8) = *reinterpret_cast<const short8*>(sq + 8);
    *reinterpret_cast<short8*>(kdst)     = *reinterpret_cast<const short8*>(sk);
    *reinterpret_cast<short8*>(kdst + 8) = *reinterpret_cast<const short8*>(sk + 8);
  }
  // v writeout: 128 dd-rows x 32 t, coalesced 16B stores
  {
    int dd = tid >> 1, half = tid & 1;
    int bh = b*HH + (dd >> 5);
    short8 s0 = *reinterpret_cast<const short8*>(&vT[dd*40 + half*16]);
    short8 s1 = *reinterpret_cast<const short8*>(&vT[dd*40 + half*16 + 8]);
    bf16* dst = vtg + ((size_t)bh*32 + (dd & 31))*TT + t0 + half*16;
    *reinterpret_cast<short8*>(dst) = s0;
    *reinterpret_cast<short8*>(dst + 8) = s1;
  }
}

// ---------------- Kernel 2: fused attention ----------------
// Block = (b, qt): 16 q-rows. 1024 blocks -> 4 blocks/CU, 16 waves/CU.
// Wave w owns contiguous 32-k chunk kc = i*4+w per iter, all 4 heads.
// attn_w: in-register head sum -> wave-private LDS stage (stride 36) ->
// 128B-contiguous f32x4 stores. PV: permuted-k register trick. ctx partials
// reduced across waves through LDS at the end, written bf16.
__global__ __launch_bounds__(256) void attn_kernel(const bf16* __restrict__ qg,
    const bf16* __restrict__ kg, const bf16* __restrict__ vtg,
    float* __restrict__ attn_out, bf16* __restrict__ ctxg) {
  // XCD swizzle: 1024 blocks = 8 XCDs x 128; each XCD owns one batch b.
  int wgid = (blockIdx.x & 7)*128 + (blockIdx.x >> 3);
  int b = wgid >> 7, qt = wgid & 127;
  int wave = threadIdx.x >> 6, lane = threadIdx.x & 63;
  int lr = lane & 15, lq = lane >> 4;
  __shared__ float S[4*16*132];          // 33792 B; per-wave 2112-float slices
  float* Sw = S + wave*2112;             // sdl | aw-stage (16x36) | sRed (16x132)
  const bf16* qb = qg + ((size_t)(b*HH)*TT + (size_t)qt*16)*32;
  const bf16* kb = kg + (size_t)(b*HH)*TT*32;
  const bf16* vb = vtg + (size_t)(b*HH)*32*TT;
  f32x4 z = {0.f,0.f,0.f,0.f};

  // Q B-frags, all heads: lane holds Q[q=lr][d=lq*8+j]
  short8 aq[4];
  #pragma unroll
  for (int h = 0; h < 4; ++h)
    aq[h] = ldg8(qb + (size_t)h*TT*32 + lr*32 + lq*8);

  // ---- pass 1: denominators. lane holds S[q=lr][k=kc*32(+16)+lq*4+r]
  float rs[4] = {0.f,0.f,0.f,0.f};
  #pragma unroll 1
  for (int i = 0; i < 16; ++i) {
    int kc = i*4 + wave;
    #pragma unroll
    for (int h = 0; h < 4; ++h) {
      const bf16* kph = kb + (size_t)h*TT*32 + (size_t)kc*32*32;
      short8 kf0 = ldg8(kph + lr*32 + lq*8);
      short8 kf1 = ldg8(kph + (16+lr)*32 + lq*8);
      f32x4 s0 = MFMA16(kf0, aq[h], z);
      f32x4 s1 = MFMA16(kf1, aq[h], z);
      #pragma unroll
      for (int r = 0; r < 4; ++r)
        rs[h] += exp2f(s0[r]*S2LOG) + exp2f(s1[r]*S2LOG);
    }
  }
  #pragma unroll
  for (int h = 0; h < 4; ++h) {
    rs[h] += __shfl_xor(rs[h], 16, 64);
    rs[h] += __shfl_xor(rs[h], 32, 64);
  }
  if (lq == 0) {
    #pragma unroll
    for (int h = 0; h < 4; ++h) Sw[h*16 + lr] = rs[h];
  }
  __syncthreads();
  float lb[4];
  #pragma unroll
  for (int h = 0; h < 4; ++h)
    lb[h] = -log2f(S[0*2112 + h*16 + lr] + S[1*2112 + h*16 + lr]
                 + S[2*2112 + h*16 + lr] + S[3*2112 + h*16 + lr]);
  __syncthreads();

  // ---- pass 2: normalized P -> attn_w + PV
  f32x4 acc[4][2];   // [h][dt]: q = lq*4+r, d = h*32+dt*16+lr
  #pragma unroll
  for (int h = 0; h < 4; ++h)
    #pragma unroll
    for (int dt = 0; dt < 2; ++dt) acc[h][dt] = z;

  float* awr = attn_out + (size_t)(b*TT + qt*16)*TT;
  int srow = lane >> 2, sc8 = (lane & 3)*8;
  #pragma unroll 1
  for (int i = 0; i < 16; ++i) {
    int kc = i*4 + wave;
    f32x4 aw0 = z, aw1 = z;
    #pragma unroll
    for (int h = 0; h < 4; ++h) {
      const bf16* kph = kb + (size_t)h*TT*32 + (size_t)kc*32*32;
      short8 kf0 = ldg8(kph + lr*32 + lq*8);
      short8 kf1 = ldg8(kph + (16+lr)*32 + lq*8);
      f32x4 s0 = MFMA16(kf0, aq[h], z);
      f32x4 s1 = MFMA16(kf1, aq[h], z);
      f32x4 p0, p1;
      #pragma unroll
      for (int r = 0; r < 4; ++r) {
        p0[r] = exp2f(fmaf(s0[r], S2LOG, lb[h]));
        p1[r] = exp2f(fmaf(s1[r], S2LOG, lb[h]));
      }
      aw0 += p0; aw1 += p1;
      short8 ap;
      #pragma unroll
      for (int r = 0; r < 4; ++r) { ap[r] = f2bs(p0[r]); ap[4+r] = f2bs(p1[r]); }
      const bf16* vph = vb + (size_t)h*32*TT + kc*32;
      #pragma unroll
      for (int dt = 0; dt < 2; ++dt) {
        const bf16* vp = vph + (size_t)(dt*16 + lr)*TT;
        short4v lo = ldg4(vp + lq*4);
        short4v hi = ldg4(vp + 16 + lq*4);
        short8 vf;
        #pragma unroll
        for (int j = 0; j < 4; ++j) { vf[j] = lo[j]; vf[4+j] = hi[j]; }
        acc[h][dt] = MFMA16(ap, vf, acc[h][dt]);
      }
    }
    // wave-private LDS stage (stride 36: uniform 8-lanes-per-bank-group)
    *reinterpret_cast<f32x4*>(&Sw[lr*36 + lq*4])      = aw0 * 0.25f;
    *reinterpret_cast<f32x4*>(&Sw[lr*36 + 16 + lq*4]) = aw1 * 0.25f;
    f32x4 w0 = *reinterpret_cast<const f32x4*>(&Sw[srow*36 + sc8]);
    f32x4 w1 = *reinterpret_cast<const f32x4*>(&Sw[srow*36 + sc8 + 4]);
    float* dst = awr + (size_t)srow*TT + kc*32 + sc8;
    *reinterpret_cast<f32x4*>(dst)     = w0;
    *reinterpret_cast<f32x4*>(dst + 4) = w1;
  }

  // ---- cross-wave ctx reduction (k-split partials), bf16 out
  #pragma unroll
  for (int h = 0; h < 4; ++h)
    #pragma unroll
    for (int dt = 0; dt < 2; ++dt)
      #pragma unroll
      for (int r = 0; r < 4; ++r)
        Sw[(lq*4 + r)*132 + h*32 + dt*16 + lr] = acc[h][dt][r];
  __syncthreads();
  {
    int q = threadIdx.x >> 4, d0 = (threadIdx.x & 15)*8;
    float v[8];
    #pragma unroll
    for (int j = 0; j < 8; ++j)
      v[j] = S[0*2112 + q*132 + d0 + j] + S[1*2112 + q*132 + d0 + j]
           + S[2*2112 + q*132 + d0 + j] + S[3*2112 + q*132 + d0 + j];
    short8 o;
    #pragma unroll
    for (int j = 0; j < 8; ++j) o[j] = f2bs(v[j]);
    *reinterpret_cast<short8*>(ctxg + (size_t)(b*TT + qt*16 + q)*128 + d0) = o;
  }
}

// ---------------- Kernel 3: MFMA out-proj + residual + LayerNorm ------------
__global__ __launch_bounds__(256) void outln_kernel(const bf16* __restrict__ ctxg,
    const float* __restrict__ lob, const float* __restrict__ Wo,
    const float* __restrict__ bo, const float* __restrict__ gamma,
    const float* __restrict__ beta, float* __restrict__ outg) {
  __shared__ float sX[32*132];
  __shared__ float sPar[256];   // gamma, beta
  int tid = threadIdx.x, wave = tid >> 6, lane = tid & 63;
  int lr = lane & 15, lq = lane >> 4;
  int r0 = blockIdx.x * 32;
  if (tid < 128) { sPar[tid] = gamma[tid]; sPar[128+tid] = beta[tid]; }
  f32x4 z = {0.f,0.f,0.f,0.f};
  short8 actx[2][4];
  #pragma unroll
  for (int mt = 0; mt < 2; ++mt)
    #pragma unroll
    for (int kt = 0; kt < 4; ++kt)
      actx[mt][kt] = ldg8(ctxg + (size_t)(r0 + mt*16 + lr)*128 + kt*32 + lq*8);
  for (int nt = wave; nt < 8; nt += 4) {
    f32x4 acc0 = z, acc1 = z;
    #pragma unroll
    for (int kt = 0; kt < 4; ++kt) {
      short8 bfrag = ldcvt8(Wo + (size_t)(nt*16 + lr)*128 + kt*32 + lq*8);
      acc0 = MFMA16(actx[0][kt], bfrag, acc0);
      acc1 = MFMA16(actx[1][kt], bfrag, acc1);
    }
    int d = nt*16 + lr;
    float bias = bo[d];
    #pragma unroll
    for (int mt = 0; mt < 2; ++mt) {
      f32x4 acc = mt ? acc1 : acc0;
      #pragma unroll
      for (int r = 0; r < 4; ++r) {
        int row = mt*16 + lq*4 + r;
        sX[row*132 + d] = acc[r] + bias + lob[(size_t)(r0 + row)*128 + d];
      }
    }
  }
  __syncthreads();
  {
    int row = tid >> 3, j = tid & 7;
    const float* xp = &sX[row*132 + j*16];
    f32x4 x[4];
    #pragma unroll
    for (int v = 0; v < 4; ++v) x[v] = *reinterpret_cast<const f32x4*>(xp + v*4);
    float sum = 0.f, sq = 0.f;
    #pragma unroll
    for (int v = 0; v < 4; ++v)
      #pragma unroll
      for (int e = 0; e < 4; ++e) { sum += x[v][e]; sq += x[v][e]*x[v][e]; }
    #pragma unroll
    for (int mdx = 1; mdx < 8; mdx <<= 1) {
      sum += __shfl_xor(sum, mdx, 64);
      sq  += __shfl_xor(sq,  mdx, 64);
    }
    float mu = sum * (1.0f/128.0f);
    float rstd = rsqrtf(sq*(1.0f/128.0f) - mu*mu + 1e-5f);
    float* op = outg + (size_t)(r0 + row)*128 + j*16;
    #pragma unroll
    for (int v = 0; v < 4; ++v) {
      f32x4 o;
      #pragma unroll
      for (int e = 0; e < 4; ++e) {
        int d = j*16 + v*4 + e;
        o[e] = (x[v][e] - mu)*rstd*sPar[d] + sPar[128+d];
      }
      *reinterpret_cast<f32x4*>(op + v*4) = o;
    }
  }
}

extern "C" void kernel_launch(void* const* d_in, const int* in_sizes, int n_in,
                              void* d_out, int out_size, void* d_ws, size_t ws_size,
                              hipStream_t stream) {
  const float* lob    = (const float*)d_in[0];
  const float* hawkes = (const float*)d_in[1];
  const float* Wp     = (const float*)d_in[2];
  const float* bp     = (const float*)d_in[3];
  const float* Win    = (const float*)d_in[4];
  const float* binp   = (const float*)d_in[5];
  const float* Wo     = (const float*)d_in[6];
  const float* bo     = (const float*)d_in[7];
  const float* gamma  = (const float*)d_in[8];
  const float* beta   = (const float*)d_in[9];
  float* outg = (float*)d_out;
  float* attn_out = outg + (size_t)BT*128;   // out (B,T,128) then attn_w (B,T,T)

  char* ws = (char*)d_ws;
  bf16*  qg   = (bf16*)(ws);                                   // 4 MB
  bf16*  kg   = (bf16*)(ws + (size_t)4*1024*1024);             // 4 MB
  bf16*  vtg  = (bf16*)(ws + (size_t)8*1024*1024);             // 4 MB (B,H,32,T)
  bf16*  ctxg = (bf16*)(ws + (size_t)12*1024*1024);            // 4 MB (B,T,128)

  proj_kernel<<<BT/32, 256, 0, stream>>>(lob, hawkes, Wp, bp, Win, binp, qg, kg, vtg);
  attn_kernel<<<BB*(TT/16), 256, 0, stream>>>(qg, kg, vtg, attn_out, ctxg);
  outln_kernel<<<512, 256, 0, stream>>>(ctxg, lob, Wo, bo, gamma, beta, outg);
}

// Round 6
// 283.451 us; speedup vs baseline: 1.2617x; 1.2617x over previous
//
#include <hip/hip_runtime.h>
#include <hip/hip_bf16.h>
#include <math.h>

#define TT 2048
#define BB 8
#define DD 128
#define HH 4
#define BT (BB*TT)
#define BH (BB*HH)
#define SCALE 0.1767766952966369f
#define S2LOG (SCALE * 1.4426950408889634f)   // scale * log2(e)

typedef __attribute__((ext_vector_type(8))) short short8;
typedef __attribute__((ext_vector_type(4))) short short4v;
typedef __attribute__((ext_vector_type(4))) float f32x4;
typedef __hip_bfloat16 bf16;

#define MFMA16(a,b,c) __builtin_amdgcn_mfma_f32_16x16x32_bf16(a,b,c,0,0,0)

static __device__ inline short8 ldg8(const bf16* p) {
  return *reinterpret_cast<const short8*>(p);
}
static __device__ inline short4v ldg4(const bf16* p) {
  return *reinterpret_cast<const short4v*>(p);
}
static __device__ inline short f2bs(float x) {
  bf16 h = __float2bfloat16(x);
  return *reinterpret_cast<short*>(&h);
}
// fast f32->bf16 (round-half-up); safe for finite non-NaN values (P in [0,1])
static __device__ inline short fpack(float x) {
  unsigned u = *reinterpret_cast<unsigned*>(&x);
  return (short)((u + 0x8000u) >> 16);
}
// load 8 contiguous f32 from global, convert to bf16 A/B-fragment
static __device__ inline short8 ldcvt8(const float* p) {
  f32x4 f0 = *reinterpret_cast<const f32x4*>(p);
  f32x4 f1 = *reinterpret_cast<const f32x4*>(p + 4);
  short8 r;
  #pragma unroll
  for (int i = 0; i < 4; ++i) { r[i] = f2bs(f0[i]); r[4+i] = f2bs(f1[i]); }
  return r;
}

// ---------------- Kernel 1: MFMA projections (unchanged from R4) -----------
__global__ __launch_bounds__(256) void proj_kernel(
    const float* __restrict__ lob, const float* __restrict__ hawkes,
    const float* __restrict__ Wp, const float* __restrict__ bp,
    const float* __restrict__ Win, const float* __restrict__ binp,
    bf16* __restrict__ qg, bf16* __restrict__ kg, bf16* __restrict__ vtg) {
  __shared__ bf16 hT[32*136];   // h tile; reused as q staging after ah read
  __shared__ bf16 sK[32*136];   // k staging
  __shared__ bf16 vT[128*40];   // v^T staging
  int tid = threadIdx.x;
  int wave = tid >> 6, lane = tid & 63;
  int lr = lane & 15, lq = lane >> 4;
  int r0 = blockIdx.x * 32;
  int b  = r0 >> 11, t0 = r0 & 2047;
  f32x4 z = {0.f,0.f,0.f,0.f};

  short8 alob[2][4], ahk[2];
  #pragma unroll
  for (int mt = 0; mt < 2; ++mt) {
    const float* lp = lob + (size_t)(r0 + mt*16 + lr)*128;
    #pragma unroll
    for (int kt = 0; kt < 4; ++kt) alob[mt][kt] = ldcvt8(lp + kt*32 + lq*8);
    ahk[mt] = ldcvt8(hawkes + (size_t)(r0 + mt*16 + lr)*32 + lq*8);
  }

  for (int nt = wave; nt < 8; nt += 4) {
    int cn = nt*16;
    short8 bfrag = ldcvt8(Wp + (size_t)(cn + lr)*32 + lq*8);
    float bias = bp[cn + lr];
    #pragma unroll
    for (int mt = 0; mt < 2; ++mt) {
      f32x4 c = MFMA16(ahk[mt], bfrag, z);
      #pragma unroll
      for (int r = 0; r < 4; ++r)
        hT[(mt*16 + lq*4 + r)*136 + cn + lr] = __float2bfloat16(c[r] + bias);
    }
  }
  __syncthreads();

  short8 ah[2][4];
  #pragma unroll
  for (int mt = 0; mt < 2; ++mt)
    #pragma unroll
    for (int kt = 0; kt < 4; ++kt)
      ah[mt][kt] = *reinterpret_cast<const short8*>(&hT[(mt*16 + lr)*136 + kt*32 + lq*8]);
  __syncthreads();   // hT free -> reuse as q staging

  for (int nt = wave; nt < 24; nt += 4) {
    int which = nt >> 3;
    int c = (nt & 7)*16 + lr;
    const float* wrow = Win + (size_t)(which*128 + c)*128;
    float bias = binp[which*128 + c];
    f32x4 acc0 = z, acc1 = z;
    #pragma unroll
    for (int kt = 0; kt < 4; ++kt) {
      short8 bfrag = ldcvt8(wrow + kt*32 + lq*8);
      if (which == 0) {
        acc0 = MFMA16(alob[0][kt], bfrag, acc0);
        acc1 = MFMA16(alob[1][kt], bfrag, acc1);
      } else {
        acc0 = MFMA16(ah[0][kt], bfrag, acc0);
        acc1 = MFMA16(ah[1][kt], bfrag, acc1);
      }
    }
    #pragma unroll
    for (int mt = 0; mt < 2; ++mt) {
      f32x4 acc = mt ? acc1 : acc0;
      #pragma unroll
      for (int r = 0; r < 4; ++r) {
        int row = mt*16 + lq*4 + r;
        float val = acc[r] + bias;
        if (which == 0)      hT[row*136 + c] = __float2bfloat16(val);
        else if (which == 1) sK[row*136 + c] = __float2bfloat16(val);
        else                 vT[c*40 + row]  = __float2bfloat16(val);
      }
    }
  }
  __syncthreads();

  // q,k writeout: 256 threads x 32B, fully contiguous 4KB per head
  {
    int head = tid >> 6, tt = (tid >> 1) & 31, half = tid & 1;
    const bf16* sq = &hT[tt*136 + head*32 + half*16];
    const bf16* sk = &sK[tt*136 + head*32 + half*16];
    bf16* qdst = qg + ((size_t)(b*HH + head)*TT + t0 + tt)*32 + half*16;
    bf16* kdst = kg + ((size_t)(b*HH + head)*TT + t0 + tt)*32 + half*16;
    *reinterpret_cast<short8*>(qdst)     = *reinterpret_cast<const short8*>(sq);
    *reinterpret_cast<short8*>(qdst + 8) = *reinterpret_cast<const short8*>(sq + 8);
    *reinterpret_cast<short8*>(kdst)     = *reinterpret_cast<const short8*>(sk);
    *reinterpret_cast<short8*>(kdst + 8) = *reinterpret_cast<const short8*>(sk + 8);
  }
  // v writeout: 128 dd-rows x 32 t, coalesced 16B stores
  {
    int dd = tid >> 1, half = tid & 1;
    int bh = b*HH + (dd >> 5);
    short8 s0 = *reinterpret_cast<const short8*>(&vT[dd*40 + half*16]);
    short8 s1 = *reinterpret_cast<const short8*>(&vT[dd*40 + half*16 + 8]);
    bf16* dst = vtg + ((size_t)bh*32 + (dd & 31))*TT + t0 + half*16;
    *reinterpret_cast<short8*>(dst) = s0;
    *reinterpret_cast<short8*>(dst + 8) = s1;
  }
}

// ---------------- Kernel 2: fused attention (R5) ----------------
// Block = (b, qt): 32 q-rows, 512 blocks. HEAD-split waves (wave = head),
// with explicit register double-buffer prefetch of next chunk's K AND V
// (the R1 property whose removal caused R2/R4 regressions).
// Swapped QK^T (lane: q=lr, k=4lq+r) -> P normalized in-register ->
// (a) vectorized b128 stores to conflict-free stride-36 plds for the
//     cross-head attn_w mean (1 barrier/chunk, double-buffered),
// (b) PV straight from registers via permuted-k trick.
// ctx written coalesced via LDS stage at end.
__global__ __launch_bounds__(256) void attn_kernel(const bf16* __restrict__ qg,
    const bf16* __restrict__ kg, const bf16* __restrict__ vtg,
    float* __restrict__ attn_out, bf16* __restrict__ ctxg) {
  // XCD swizzle: 512 blocks = 8 XCDs x 64; each XCD owns one batch b.
  int wgid = (blockIdx.x & 7)*64 + (blockIdx.x >> 3);
  int b = wgid >> 6, qt = wgid & 63;
  int tid = threadIdx.x;
  int head = tid >> 6, lane = tid & 63;
  int lr = lane & 15, lq = lane >> 4;
  int bh = b*HH + head;
  __shared__ float plds[2][4][32*36];   // 36864 B -> 4 blocks/CU
  const bf16* qp = qg + ((size_t)bh*TT + (size_t)qt*32)*32;
  const bf16* kb = kg + (size_t)bh*TT*32;
  const bf16* vb = vtg + (size_t)bh*32*TT;
  f32x4 z = {0.f,0.f,0.f,0.f};

  // Q B-frags: lane holds Q[q=m*16+lr][d=lq*8+j]
  short8 aq0 = ldg8(qp + lr*32 + lq*8);
  short8 aq1 = ldg8(qp + (16+lr)*32 + lq*8);

  // ---- pass 1: denominators (wave-local; head-split => no LDS exchange)
  float rs0 = 0.f, rs1 = 0.f;
  {
    short8 kA0 = ldg8(kb + (size_t)lr*32 + lq*8);
    short8 kA1 = ldg8(kb + (size_t)(16+lr)*32 + lq*8);
    short8 kB0, kB1;
#define P1STEP(KC0, KC1, KN0, KN1, NCC) { \
    int nc_ = (NCC); \
    KN0 = ldg8(kb + (size_t)(nc_*32 + lr)*32 + lq*8); \
    KN1 = ldg8(kb + (size_t)(nc_*32 + 16 + lr)*32 + lq*8); \
    f32x4 sa0 = MFMA16(KC0, aq0, z), sb0 = MFMA16(KC1, aq0, z); \
    f32x4 sa1 = MFMA16(KC0, aq1, z), sb1 = MFMA16(KC1, aq1, z); \
    _Pragma("unroll") for (int r = 0; r < 4; ++r) { \
      rs0 += exp2f(sa0[r]*S2LOG) + exp2f(sb0[r]*S2LOG); \
      rs1 += exp2f(sa1[r]*S2LOG) + exp2f(sb1[r]*S2LOG); } }
    #pragma unroll 1
    for (int c = 0; c < 64; c += 2) {
      P1STEP(kA0, kA1, kB0, kB1, c+1);
      P1STEP(kB0, kB1, kA0, kA1, (c+2 < 64) ? c+2 : 0);
    }
#undef P1STEP
  }
  rs0 += __shfl_xor(rs0, 16, 64); rs0 += __shfl_xor(rs0, 32, 64);
  rs1 += __shfl_xor(rs1, 16, 64); rs1 += __shfl_xor(rs1, 32, 64);
  float lb0 = -log2f(rs0);   // q = qt*32 + lr
  float lb1 = -log2f(rs1);   // q = qt*32 + 16 + lr

  // ---- pass 2: normalized P -> attn_w mean (via plds) + PV (registers)
  f32x4 acc00 = z, acc01 = z, acc10 = z, acc11 = z;  // [m][dt]
  float* awr = attn_out + (size_t)(b*TT + qt*32)*TT;
  int mq = tid >> 3, mk = (tid & 7)*4;   // mean-phase mapping: 8 thr/row

  short8 kA0 = ldg8(kb + (size_t)lr*32 + lq*8);
  short8 kA1 = ldg8(kb + (size_t)(16+lr)*32 + lq*8);
  short4v vA00 = ldg4(vb + (size_t)lr*TT + lq*4);
  short4v vA01 = ldg4(vb + (size_t)lr*TT + 16 + lq*4);
  short4v vA10 = ldg4(vb + (size_t)(16+lr)*TT + lq*4);
  short4v vA11 = ldg4(vb + (size_t)(16+lr)*TT + 16 + lq*4);
  short8 kB0, kB1; short4v vB00, vB01, vB10, vB11;

#define P2STEP(KC, KC0, KC1, VC00, VC01, VC10, VC11, KN0, KN1, VN00, VN01, VN10, VN11, NCC) { \
    int kc_ = (KC); int nc_ = (NCC); int pb_ = kc_ & 1; \
    KN0 = ldg8(kb + (size_t)(nc_*32 + lr)*32 + lq*8); \
    KN1 = ldg8(kb + (size_t)(nc_*32 + 16 + lr)*32 + lq*8); \
    VN00 = ldg4(vb + (size_t)lr*TT + nc_*32 + lq*4); \
    VN01 = ldg4(vb + (size_t)lr*TT + nc_*32 + 16 + lq*4); \
    VN10 = ldg4(vb + (size_t)(16+lr)*TT + nc_*32 + lq*4); \
    VN11 = ldg4(vb + (size_t)(16+lr)*TT + nc_*32 + 16 + lq*4); \
    f32x4 s00 = MFMA16(KC0, aq0, z), s10 = MFMA16(KC1, aq0, z); \
    f32x4 s01 = MFMA16(KC0, aq1, z), s11 = MFMA16(KC1, aq1, z); \
    f32x4 p00, p10, p01, p11; \
    _Pragma("unroll") for (int r = 0; r < 4; ++r) { \
      p00[r] = exp2f(fmaf(s00[r], S2LOG, lb0)); \
      p10[r] = exp2f(fmaf(s10[r], S2LOG, lb0)); \
      p01[r] = exp2f(fmaf(s01[r], S2LOG, lb1)); \
      p11[r] = exp2f(fmaf(s11[r], S2LOG, lb1)); } \
    { float* pw = &plds[pb_][head][0]; \
      *reinterpret_cast<f32x4*>(pw + lr*36 + lq*4)           = p00; \
      *reinterpret_cast<f32x4*>(pw + lr*36 + 16 + lq*4)      = p10; \
      *reinterpret_cast<f32x4*>(pw + (16+lr)*36 + lq*4)      = p01; \
      *reinterpret_cast<f32x4*>(pw + (16+lr)*36 + 16 + lq*4) = p11; } \
    short8 ap0, ap1; \
    _Pragma("unroll") for (int r = 0; r < 4; ++r) { \
      ap0[r] = fpack(p00[r]); ap0[4+r] = fpack(p10[r]); \
      ap1[r] = fpack(p01[r]); ap1[4+r] = fpack(p11[r]); } \
    __syncthreads(); \
    { const float* pr = &plds[pb_][0][0]; \
      f32x4 mv = *reinterpret_cast<const f32x4*>(pr + mq*36 + mk); \
      mv = mv + *reinterpret_cast<const f32x4*>(pr + 1152 + mq*36 + mk); \
      mv = mv + *reinterpret_cast<const f32x4*>(pr + 2304 + mq*36 + mk); \
      mv = mv + *reinterpret_cast<const f32x4*>(pr + 3456 + mq*36 + mk); \
      *reinterpret_cast<f32x4*>(awr + (size_t)mq*TT + kc_*32 + mk) = mv * 0.25f; } \
    short8 vf0, vf1; \
    _Pragma("unroll") for (int j = 0; j < 4; ++j) { \
      vf0[j] = VC00[j]; vf0[4+j] = VC01[j]; \
      vf1[j] = VC10[j]; vf1[4+j] = VC11[j]; } \
    acc00 = MFMA16(ap0, vf0, acc00); acc01 = MFMA16(ap0, vf1, acc01); \
    acc10 = MFMA16(ap1, vf0, acc10); acc11 = MFMA16(ap1, vf1, acc11); }

  #pragma unroll 1
  for (int c = 0; c < 64; c += 2) {
    P2STEP(c,   kA0, kA1, vA00, vA01, vA10, vA11,
                kB0, kB1, vB00, vB01, vB10, vB11, c+1);
    P2STEP(c+1, kB0, kB1, vB00, vB01, vB10, vB11,
                kA0, kA1, vA00, vA01, vA10, vA11, (c+2 < 64) ? c+2 : 0);
  }
#undef P2STEP

  // ---- ctx writeout: stage f32 in LDS (reuse plds), coalesced bf16 stores
  __syncthreads();
  float* sX = &plds[0][0][0];   // 32 x 132 floats = 16.9 KB (fits buf0 region)
  #pragma unroll
  for (int m = 0; m < 2; ++m) {
    f32x4 a0 = m ? acc10 : acc00;
    f32x4 a1 = m ? acc11 : acc01;
    #pragma unroll
    for (int r = 0; r < 4; ++r) {
      int row = m*16 + lq*4 + r;
      sX[row*132 + head*32 + lr]      = a0[r];
      sX[row*132 + head*32 + 16 + lr] = a1[r];
    }
  }
  __syncthreads();
  {
    int q = tid >> 3, d0 = (tid & 7)*16;
    const float* xp = &sX[q*132 + d0];
    f32x4 x0 = *reinterpret_cast<const f32x4*>(xp);
    f32x4 x1 = *reinterpret_cast<const f32x4*>(xp + 4);
    f32x4 x2 = *reinterpret_cast<const f32x4*>(xp + 8);
    f32x4 x3 = *reinterpret_cast<const f32x4*>(xp + 12);
    short8 o0, o1;
    #pragma unroll
    for (int j = 0; j < 4; ++j) {
      o0[j] = f2bs(x0[j]); o0[4+j] = f2bs(x1[j]);
      o1[j] = f2bs(x2[j]); o1[4+j] = f2bs(x3[j]);
    }
    bf16* dst = ctxg + (size_t)(b*TT + qt*32 + q)*128 + d0;
    *reinterpret_cast<short8*>(dst)     = o0;
    *reinterpret_cast<short8*>(dst + 8) = o1;
  }
}

// ---------------- Kernel 3: MFMA out-proj + residual + LayerNorm ------------
__global__ __launch_bounds__(256) void outln_kernel(const bf16* __restrict__ ctxg,
    const float* __restrict__ lob, const float* __restrict__ Wo,
    const float* __restrict__ bo, const float* __restrict__ gamma,
    const float* __restrict__ beta, float* __restrict__ outg) {
  __shared__ float sX[32*132];
  __shared__ float sPar[256];   // gamma, beta
  int tid = threadIdx.x, wave = tid >> 6, lane = tid & 63;
  int lr = lane & 15, lq = lane >> 4;
  int r0 = blockIdx.x * 32;
  if (tid < 128) { sPar[tid] = gamma[tid]; sPar[128+tid] = beta[tid]; }
  f32x4 z = {0.f,0.f,0.f,0.f};
  short8 actx[2][4];
  #pragma unroll
  for (int mt = 0; mt < 2; ++mt)
    #pragma unroll
    for (int kt = 0; kt < 4; ++kt)
      actx[mt][kt] = ldg8(ctxg + (size_t)(r0 + mt*16 + lr)*128 + kt*32 + lq*8);
  for (int nt = wave; nt < 8; nt += 4) {
    f32x4 acc0 = z, acc1 = z;
    #pragma unroll
    for (int kt = 0; kt < 4; ++kt) {
      short8 bfrag = ldcvt8(Wo + (size_t)(nt*16 + lr)*128 + kt*32 + lq*8);
      acc0 = MFMA16(actx[0][kt], bfrag, acc0);
      acc1 = MFMA16(actx[1][kt], bfrag, acc1);
    }
    int d = nt*16 + lr;
    float bias = bo[d];
    #pragma unroll
    for (int mt = 0; mt < 2; ++mt) {
      f32x4 acc = mt ? acc1 : acc0;
      #pragma unroll
      for (int r = 0; r < 4; ++r) {
        int row = mt*16 + lq*4 + r;
        sX[row*132 + d] = acc[r] + bias + lob[(size_t)(r0 + row)*128 + d];
      }
    }
  }
  __syncthreads();
  {
    int row = tid >> 3, j = tid & 7;
    const float* xp = &sX[row*132 + j*16];
    f32x4 x[4];
    #pragma unroll
    for (int v = 0; v < 4; ++v) x[v] = *reinterpret_cast<const f32x4*>(xp + v*4);
    float sum = 0.f, sq = 0.f;
    #pragma unroll
    for (int v = 0; v < 4; ++v)
      #pragma unroll
      for (int e = 0; e < 4; ++e) { sum += x[v][e]; sq += x[v][e]*x[v][e]; }
    #pragma unroll
    for (int mdx = 1; mdx < 8; mdx <<= 1) {
      sum += __shfl_xor(sum, mdx, 64);
      sq  += __shfl_xor(sq,  mdx, 64);
    }
    float mu = sum * (1.0f/128.0f);
    float rstd = rsqrtf(sq*(1.0f/128.0f) - mu*mu + 1e-5f);
    float* op = outg + (size_t)(r0 + row)*128 + j*16;
    #pragma unroll
    for (int v = 0; v < 4; ++v) {
      f32x4 o;
      #pragma unroll
      for (int e = 0; e < 4; ++e) {
        int d = j*16 + v*4 + e;
        o[e] = (x[v][e] - mu)*rstd*sPar[d] + sPar[128+d];
      }
      *reinterpret_cast<f32x4*>(op + v*4) = o;
    }
  }
}

extern "C" void kernel_launch(void* const* d_in, const int* in_sizes, int n_in,
                              void* d_out, int out_size, void* d_ws, size_t ws_size,
                              hipStream_t stream) {
  const float* lob    = (const float*)d_in[0];
  const float* hawkes = (const float*)d_in[1];
  const float* Wp     = (const float*)d_in[2];
  const float* bp     = (const float*)d_in[3];
  const float* Win    = (const float*)d_in[4];
  const float* binp   = (const float*)d_in[5];
  const float* Wo     = (const float*)d_in[6];
  const float* bo     = (const float*)d_in[7];
  const float* gamma  = (const float*)d_in[8];
  const float* beta   = (const float*)d_in[9];
  float* outg = (float*)d_out;
  float* attn_out = outg + (size_t)BT*128;   // out (B,T,128) then attn_w (B,T,T)

  char* ws = (char*)d_ws;
  bf16*  qg   = (bf16*)(ws);                                   // 4 MB
  bf16*  kg   = (bf16*)(ws + (size_t)4*1024*1024);             // 4 MB
  bf16*  vtg  = (bf16*)(ws + (size_t)8*1024*1024);             // 4 MB (B,H,32,T)
  bf16*  ctxg = (bf16*)(ws + (size_t)12*1024*1024);            // 4 MB (B,T,128)

  proj_kernel<<<BT/32, 256, 0, stream>>>(lob, hawkes, Wp, bp, Win, binp, qg, kg, vtg);
  attn_kernel<<<BB*(TT/32), 256, 0, stream>>>(qg, kg, vtg, attn_out, ctxg);
  outln_kernel<<<512, 256, 0, stream>>>(ctxg, lob, Wo, bo, gamma, beta, outg);
}

// Round 7
// 278.395 us; speedup vs baseline: 1.2846x; 1.0182x over previous
//
#include <hip/hip_runtime.h>
#include <hip/hip_bf16.h>
#include <math.h>

#define TT 2048
#define BB 8
#define DD 128
#define HH 4
#define BT (BB*TT)
#define BH (BB*HH)
#define SCALE 0.1767766952966369f
#define S2LOG (SCALE * 1.4426950408889634f)   // scale * log2(e)

typedef __attribute__((ext_vector_type(8))) short short8;
typedef __attribute__((ext_vector_type(4))) short short4v;
typedef __attribute__((ext_vector_type(4))) float f32x4;
typedef __attribute__((ext_vector_type(4))) unsigned u32x4;
typedef __hip_bfloat16 bf16;

#define MFMA16(a,b,c) __builtin_amdgcn_mfma_f32_16x16x32_bf16(a,b,c,0,0,0)

static __device__ inline short8 ldg8(const bf16* p) {
  return *reinterpret_cast<const short8*>(p);
}
static __device__ inline short4v ldg4(const bf16* p) {
  return *reinterpret_cast<const short4v*>(p);
}
static __device__ inline short f2bs(float x) {
  bf16 h = __float2bfloat16(x);
  return *reinterpret_cast<short*>(&h);
}
// single-instruction pack: two f32 -> one u32 holding {bf16(lo), bf16(hi)}
static __device__ inline unsigned cvtpk(float lo, float hi) {
  unsigned r;
  asm("v_cvt_pk_bf16_f32 %0, %1, %2" : "=v"(r) : "v"(lo), "v"(hi));
  return r;
}
// load 8 contiguous f32 from global, convert to bf16 A/B-fragment
static __device__ inline short8 ldcvt8(const float* p) {
  f32x4 f0 = *reinterpret_cast<const f32x4*>(p);
  f32x4 f1 = *reinterpret_cast<const f32x4*>(p + 4);
  short8 r;
  #pragma unroll
  for (int i = 0; i < 4; ++i) { r[i] = f2bs(f0[i]); r[4+i] = f2bs(f1[i]); }
  return r;
}

// ---------------- Kernel 1: MFMA projections (unchanged from R6) -----------
__global__ __launch_bounds__(256) void proj_kernel(
    const float* __restrict__ lob, const float* __restrict__ hawkes,
    const float* __restrict__ Wp, const float* __restrict__ bp,
    const float* __restrict__ Win, const float* __restrict__ binp,
    bf16* __restrict__ qg, bf16* __restrict__ kg, bf16* __restrict__ vtg) {
  __shared__ bf16 hT[32*136];   // h tile; reused as q staging after ah read
  __shared__ bf16 sK[32*136];   // k staging
  __shared__ bf16 vT[128*40];   // v^T staging
  int tid = threadIdx.x;
  int wave = tid >> 6, lane = tid & 63;
  int lr = lane & 15, lq = lane >> 4;
  int r0 = blockIdx.x * 32;
  int b  = r0 >> 11, t0 = r0 & 2047;
  f32x4 z = {0.f,0.f,0.f,0.f};

  short8 alob[2][4], ahk[2];
  #pragma unroll
  for (int mt = 0; mt < 2; ++mt) {
    const float* lp = lob + (size_t)(r0 + mt*16 + lr)*128;
    #pragma unroll
    for (int kt = 0; kt < 4; ++kt) alob[mt][kt] = ldcvt8(lp + kt*32 + lq*8);
    ahk[mt] = ldcvt8(hawkes + (size_t)(r0 + mt*16 + lr)*32 + lq*8);
  }

  for (int nt = wave; nt < 8; nt += 4) {
    int cn = nt*16;
    short8 bfrag = ldcvt8(Wp + (size_t)(cn + lr)*32 + lq*8);
    float bias = bp[cn + lr];
    #pragma unroll
    for (int mt = 0; mt < 2; ++mt) {
      f32x4 c = MFMA16(ahk[mt], bfrag, z);
      #pragma unroll
      for (int r = 0; r < 4; ++r)
        hT[(mt*16 + lq*4 + r)*136 + cn + lr] = __float2bfloat16(c[r] + bias);
    }
  }
  __syncthreads();

  short8 ah[2][4];
  #pragma unroll
  for (int mt = 0; mt < 2; ++mt)
    #pragma unroll
    for (int kt = 0; kt < 4; ++kt)
      ah[mt][kt] = *reinterpret_cast<const short8*>(&hT[(mt*16 + lr)*136 + kt*32 + lq*8]);
  __syncthreads();   // hT free -> reuse as q staging

  for (int nt = wave; nt < 24; nt += 4) {
    int which = nt >> 3;
    int c = (nt & 7)*16 + lr;
    const float* wrow = Win + (size_t)(which*128 + c)*128;
    float bias = binp[which*128 + c];
    f32x4 acc0 = z, acc1 = z;
    #pragma unroll
    for (int kt = 0; kt < 4; ++kt) {
      short8 bfrag = ldcvt8(wrow + kt*32 + lq*8);
      if (which == 0) {
        acc0 = MFMA16(alob[0][kt], bfrag, acc0);
        acc1 = MFMA16(alob[1][kt], bfrag, acc1);
      } else {
        acc0 = MFMA16(ah[0][kt], bfrag, acc0);
        acc1 = MFMA16(ah[1][kt], bfrag, acc1);
      }
    }
    #pragma unroll
    for (int mt = 0; mt < 2; ++mt) {
      f32x4 acc = mt ? acc1 : acc0;
      #pragma unroll
      for (int r = 0; r < 4; ++r) {
        int row = mt*16 + lq*4 + r;
        float val = acc[r] + bias;
        if (which == 0)      hT[row*136 + c] = __float2bfloat16(val);
        else if (which == 1) sK[row*136 + c] = __float2bfloat16(val);
        else                 vT[c*40 + row]  = __float2bfloat16(val);
      }
    }
  }
  __syncthreads();

  // q,k writeout: 256 threads x 32B, fully contiguous 4KB per head
  {
    int head = tid >> 6, tt = (tid >> 1) & 31, half = tid & 1;
    const bf16* sq = &hT[tt*136 + head*32 + half*16];
    const bf16* sk = &sK[tt*136 + head*32 + half*16];
    bf16* qdst = qg + ((size_t)(b*HH + head)*TT + t0 + tt)*32 + half*16;
    bf16* kdst = kg + ((size_t)(b*HH + head)*TT + t0 + tt)*32 + half*16;
    *reinterpret_cast<short8*>(qdst)     = *reinterpret_cast<const short8*>(sq);
    *reinterpret_cast<short8*>(qdst + 8) = *reinterpret_cast<const short8*>(sq + 8);
    *reinterpret_cast<short8*>(kdst)     = *reinterpret_cast<const short8*>(sk);
    *reinterpret_cast<short8*>(kdst + 8) = *reinterpret_cast<const short8*>(sk + 8);
  }
  // v writeout: 128 dd-rows x 32 t, coalesced 16B stores
  {
    int dd = tid >> 1, half = tid & 1;
    int bh = b*HH + (dd >> 5);
    short8 s0 = *reinterpret_cast<const short8*>(&vT[dd*40 + half*16]);
    short8 s1 = *reinterpret_cast<const short8*>(&vT[dd*40 + half*16 + 8]);
    bf16* dst = vtg + ((size_t)bh*32 + (dd & 31))*TT + t0 + half*16;
    *reinterpret_cast<short8*>(dst) = s0;
    *reinterpret_cast<short8*>(dst + 8) = s1;
  }
}

// ------- Kernel 2: fused attention + out-proj + residual + LayerNorm -------
// R6 attention structure (head-split waves, register double-buffer prefetch,
// permuted-k PV, 1 barrier/chunk) with:
//  (a) v_cvt_pk_bf16_f32 for the P->bf16 pack (8 insts vs ~32-48),
//  (b) outln fused as an epilogue: this block holds complete ctx rows for
//      its 32 q-rows, so ctx@Wo^T + bo + lob -> LayerNorm -> out is done
//      in-block. Kills the third kernel and the 8 MB ctx round-trip.
__global__ __launch_bounds__(256) void attn_kernel(const bf16* __restrict__ qg,
    const bf16* __restrict__ kg, const bf16* __restrict__ vtg,
    float* __restrict__ attn_out, const float* __restrict__ lobf,
    const float* __restrict__ Wo, const float* __restrict__ bo,
    const float* __restrict__ gamma, const float* __restrict__ beta,
    float* __restrict__ outg) {
  // XCD swizzle: 512 blocks = 8 XCDs x 64; each XCD owns one batch b.
  int wgid = (blockIdx.x & 7)*64 + (blockIdx.x >> 3);
  int b = wgid >> 6, qt = wgid & 63;
  int tid = threadIdx.x;
  int head = tid >> 6, lane = tid & 63;
  int lr = lane & 15, lq = lane >> 4;
  int bh = b*HH + head;
  __shared__ float plds[2][4][32*36];   // 36864 B -> 4 blocks/CU capacity
  const bf16* qp = qg + ((size_t)bh*TT + (size_t)qt*32)*32;
  const bf16* kb = kg + (size_t)bh*TT*32;
  const bf16* vb = vtg + (size_t)bh*32*TT;
  f32x4 z = {0.f,0.f,0.f,0.f};

  // Q B-frags: lane holds Q[q=m*16+lr][d=lq*8+j]
  short8 aq0 = ldg8(qp + lr*32 + lq*8);
  short8 aq1 = ldg8(qp + (16+lr)*32 + lq*8);

  // ---- pass 1: denominators (wave-local; head-split => no LDS exchange)
  float rs0 = 0.f, rs1 = 0.f;
  {
    short8 kA0 = ldg8(kb + (size_t)lr*32 + lq*8);
    short8 kA1 = ldg8(kb + (size_t)(16+lr)*32 + lq*8);
    short8 kB0, kB1;
#define P1STEP(KC0, KC1, KN0, KN1, NCC) { \
    int nc_ = (NCC); \
    KN0 = ldg8(kb + (size_t)(nc_*32 + lr)*32 + lq*8); \
    KN1 = ldg8(kb + (size_t)(nc_*32 + 16 + lr)*32 + lq*8); \
    f32x4 sa0 = MFMA16(KC0, aq0, z), sb0 = MFMA16(KC1, aq0, z); \
    f32x4 sa1 = MFMA16(KC0, aq1, z), sb1 = MFMA16(KC1, aq1, z); \
    _Pragma("unroll") for (int r = 0; r < 4; ++r) { \
      rs0 += exp2f(sa0[r]*S2LOG) + exp2f(sb0[r]*S2LOG); \
      rs1 += exp2f(sa1[r]*S2LOG) + exp2f(sb1[r]*S2LOG); } }
    #pragma unroll 1
    for (int c = 0; c < 64; c += 2) {
      P1STEP(kA0, kA1, kB0, kB1, c+1);
      P1STEP(kB0, kB1, kA0, kA1, (c+2 < 64) ? c+2 : 0);
    }
#undef P1STEP
  }
  rs0 += __shfl_xor(rs0, 16, 64); rs0 += __shfl_xor(rs0, 32, 64);
  rs1 += __shfl_xor(rs1, 16, 64); rs1 += __shfl_xor(rs1, 32, 64);
  float lb0 = -log2f(rs0);   // q = qt*32 + lr
  float lb1 = -log2f(rs1);   // q = qt*32 + 16 + lr

  // ---- pass 2: normalized P -> attn_w mean (via plds) + PV (registers)
  f32x4 acc00 = z, acc01 = z, acc10 = z, acc11 = z;  // [m][dt]
  float* awr = attn_out + (size_t)(b*TT + qt*32)*TT;
  int mq = tid >> 3, mk = (tid & 7)*4;   // mean-phase mapping: 8 thr/row

  short8 kA0 = ldg8(kb + (size_t)lr*32 + lq*8);
  short8 kA1 = ldg8(kb + (size_t)(16+lr)*32 + lq*8);
  short4v vA00 = ldg4(vb + (size_t)lr*TT + lq*4);
  short4v vA01 = ldg4(vb + (size_t)lr*TT + 16 + lq*4);
  short4v vA10 = ldg4(vb + (size_t)(16+lr)*TT + lq*4);
  short4v vA11 = ldg4(vb + (size_t)(16+lr)*TT + 16 + lq*4);
  short8 kB0, kB1; short4v vB00, vB01, vB10, vB11;

#define P2STEP(KC, KC0, KC1, VC00, VC01, VC10, VC11, KN0, KN1, VN00, VN01, VN10, VN11, NCC) { \
    int kc_ = (KC); int nc_ = (NCC); int pb_ = kc_ & 1; \
    KN0 = ldg8(kb + (size_t)(nc_*32 + lr)*32 + lq*8); \
    KN1 = ldg8(kb + (size_t)(nc_*32 + 16 + lr)*32 + lq*8); \
    VN00 = ldg4(vb + (size_t)lr*TT + nc_*32 + lq*4); \
    VN01 = ldg4(vb + (size_t)lr*TT + nc_*32 + 16 + lq*4); \
    VN10 = ldg4(vb + (size_t)(16+lr)*TT + nc_*32 + lq*4); \
    VN11 = ldg4(vb + (size_t)(16+lr)*TT + nc_*32 + 16 + lq*4); \
    f32x4 s00 = MFMA16(KC0, aq0, z), s10 = MFMA16(KC1, aq0, z); \
    f32x4 s01 = MFMA16(KC0, aq1, z), s11 = MFMA16(KC1, aq1, z); \
    f32x4 p00, p10, p01, p11; \
    _Pragma("unroll") for (int r = 0; r < 4; ++r) { \
      p00[r] = exp2f(fmaf(s00[r], S2LOG, lb0)); \
      p10[r] = exp2f(fmaf(s10[r], S2LOG, lb0)); \
      p01[r] = exp2f(fmaf(s01[r], S2LOG, lb1)); \
      p11[r] = exp2f(fmaf(s11[r], S2LOG, lb1)); } \
    { float* pw = &plds[pb_][head][0]; \
      *reinterpret_cast<f32x4*>(pw + lr*36 + lq*4)           = p00; \
      *reinterpret_cast<f32x4*>(pw + lr*36 + 16 + lq*4)      = p10; \
      *reinterpret_cast<f32x4*>(pw + (16+lr)*36 + lq*4)      = p01; \
      *reinterpret_cast<f32x4*>(pw + (16+lr)*36 + 16 + lq*4) = p11; } \
    u32x4 ua_, ub_; \
    ua_[0] = cvtpk(p00[0], p00[1]); ua_[1] = cvtpk(p00[2], p00[3]); \
    ua_[2] = cvtpk(p10[0], p10[1]); ua_[3] = cvtpk(p10[2], p10[3]); \
    ub_[0] = cvtpk(p01[0], p01[1]); ub_[1] = cvtpk(p01[2], p01[3]); \
    ub_[2] = cvtpk(p11[0], p11[1]); ub_[3] = cvtpk(p11[2], p11[3]); \
    short8 ap0 = *reinterpret_cast<short8*>(&ua_); \
    short8 ap1 = *reinterpret_cast<short8*>(&ub_); \
    __syncthreads(); \
    { const float* pr = &plds[pb_][0][0]; \
      f32x4 mv = *reinterpret_cast<const f32x4*>(pr + mq*36 + mk); \
      mv = mv + *reinterpret_cast<const f32x4*>(pr + 1152 + mq*36 + mk); \
      mv = mv + *reinterpret_cast<const f32x4*>(pr + 2304 + mq*36 + mk); \
      mv = mv + *reinterpret_cast<const f32x4*>(pr + 3456 + mq*36 + mk); \
      *reinterpret_cast<f32x4*>(awr + (size_t)mq*TT + kc_*32 + mk) = mv * 0.25f; } \
    short8 vf0, vf1; \
    _Pragma("unroll") for (int j = 0; j < 4; ++j) { \
      vf0[j] = VC00[j]; vf0[4+j] = VC01[j]; \
      vf1[j] = VC10[j]; vf1[4+j] = VC11[j]; } \
    acc00 = MFMA16(ap0, vf0, acc00); acc01 = MFMA16(ap0, vf1, acc01); \
    acc10 = MFMA16(ap1, vf0, acc10); acc11 = MFMA16(ap1, vf1, acc11); }

  #pragma unroll 1
  for (int c = 0; c < 64; c += 2) {
    P2STEP(c,   kA0, kA1, vA00, vA01, vA10, vA11,
                kB0, kB1, vB00, vB01, vB10, vB11, c+1);
    P2STEP(c+1, kB0, kB1, vB00, vB01, vB10, vB11,
                kA0, kA1, vA00, vA01, vA10, vA11, (c+2 < 64) ? c+2 : 0);
  }
#undef P2STEP

  // ---- epilogue: ctx -> sX (f32), then out-proj + residual + LayerNorm
  __syncthreads();
  size_t rowbase = (size_t)(b*TT) + (size_t)qt*32;
  float* sX  = &plds[0][0][0];   // 32 x 132 floats (ctx staging)
  float* sX2 = &plds[1][0][0];   // 32 x 132 floats (x = ctx@Wo^T + bo + lob)
  #pragma unroll
  for (int m = 0; m < 2; ++m) {
    f32x4 a0 = m ? acc10 : acc00;
    f32x4 a1 = m ? acc11 : acc01;
    #pragma unroll
    for (int r = 0; r < 4; ++r) {
      int row = m*16 + lq*4 + r;
      sX[row*132 + head*32 + lr]      = a0[r];
      sX[row*132 + head*32 + 16 + lr] = a1[r];
    }
  }
  __syncthreads();
  // ctx A-frags from sX (f32 -> bf16 via cvt_pk)
  short8 actx[2][4];
  #pragma unroll
  for (int mt = 0; mt < 2; ++mt)
    #pragma unroll
    for (int kt = 0; kt < 4; ++kt) {
      const float* cp = &sX[(mt*16 + lr)*132 + kt*32 + lq*8];
      f32x4 c0 = *reinterpret_cast<const f32x4*>(cp);
      f32x4 c1 = *reinterpret_cast<const f32x4*>(cp + 4);
      u32x4 u;
      u[0] = cvtpk(c0[0], c0[1]); u[1] = cvtpk(c0[2], c0[3]);
      u[2] = cvtpk(c1[0], c1[1]); u[3] = cvtpk(c1[2], c1[3]);
      actx[mt][kt] = *reinterpret_cast<short8*>(&u);
    }
  // out = ctx @ Wo^T + bo + lob -> sX2 (each wave: 2 of 8 N-tiles)
  for (int nt = head; nt < 8; nt += 4) {
    f32x4 acc0 = z, acc1 = z;
    #pragma unroll
    for (int kt = 0; kt < 4; ++kt) {
      short8 bfrag = ldcvt8(Wo + (size_t)(nt*16 + lr)*128 + kt*32 + lq*8);
      acc0 = MFMA16(actx[0][kt], bfrag, acc0);
      acc1 = MFMA16(actx[1][kt], bfrag, acc1);
    }
    int d = nt*16 + lr;
    float bias = bo[d];
    #pragma unroll
    for (int mt = 0; mt < 2; ++mt) {
      f32x4 acc = mt ? acc1 : acc0;
      #pragma unroll
      for (int r = 0; r < 4; ++r) {
        int row = mt*16 + lq*4 + r;
        sX2[row*132 + d] = acc[r] + bias + lobf[(rowbase + row)*128 + d];
      }
    }
  }
  __syncthreads();
  // LayerNorm: 8 threads per row, 16 f32 each
  {
    int row = tid >> 3, j = tid & 7;
    const float* xp = &sX2[row*132 + j*16];
    f32x4 x[4];
    #pragma unroll
    for (int v = 0; v < 4; ++v) x[v] = *reinterpret_cast<const f32x4*>(xp + v*4);
    float sum = 0.f, sq = 0.f;
    #pragma unroll
    for (int v = 0; v < 4; ++v)
      #pragma unroll
      for (int e = 0; e < 4; ++e) { sum += x[v][e]; sq += x[v][e]*x[v][e]; }
    #pragma unroll
    for (int mdx = 1; mdx < 8; mdx <<= 1) {
      sum += __shfl_xor(sum, mdx, 64);
      sq  += __shfl_xor(sq,  mdx, 64);
    }
    float mu = sum * (1.0f/128.0f);
    float rstd = rsqrtf(sq*(1.0f/128.0f) - mu*mu + 1e-5f);
    float* op = outg + (rowbase + row)*128 + j*16;
    #pragma unroll
    for (int v = 0; v < 4; ++v) {
      f32x4 o;
      #pragma unroll
      for (int e = 0; e < 4; ++e) {
        int d = j*16 + v*4 + e;
        o[e] = (x[v][e] - mu)*rstd*gamma[d] + beta[d];
      }
      *reinterpret_cast<f32x4*>(op + v*4) = o;
    }
  }
}

extern "C" void kernel_launch(void* const* d_in, const int* in_sizes, int n_in,
                              void* d_out, int out_size, void* d_ws, size_t ws_size,
                              hipStream_t stream) {
  const float* lob    = (const float*)d_in[0];
  const float* hawkes = (const float*)d_in[1];
  const float* Wp     = (const float*)d_in[2];
  const float* bp     = (const float*)d_in[3];
  const float* Win    = (const float*)d_in[4];
  const float* binp   = (const float*)d_in[5];
  const float* Wo     = (const float*)d_in[6];
  const float* bo     = (const float*)d_in[7];
  const float* gamma  = (const float*)d_in[8];
  const float* beta   = (const float*)d_in[9];
  float* outg = (float*)d_out;
  float* attn_out = outg + (size_t)BT*128;   // out (B,T,128) then attn_w (B,T,T)

  char* ws = (char*)d_ws;
  bf16*  qg   = (bf16*)(ws);                                   // 4 MB
  bf16*  kg   = (bf16*)(ws + (size_t)4*1024*1024);             // 4 MB
  bf16*  vtg  = (bf16*)(ws + (size_t)8*1024*1024);             // 4 MB (B,H,32,T)

  proj_kernel<<<BT/32, 256, 0, stream>>>(lob, hawkes, Wp, bp, Win, binp, qg, kg, vtg);
  attn_kernel<<<BB*(TT/32), 256, 0, stream>>>(qg, kg, vtg, attn_out,
                                              lob, Wo, bo, gamma, beta, outg);
}

// Round 8
// 275.640 us; speedup vs baseline: 1.2974x; 1.0100x over previous
//
#include <hip/hip_runtime.h>
#include <hip/hip_bf16.h>
#include <math.h>

#define TT 2048
#define BB 8
#define DD 128
#define HH 4
#define BT (BB*TT)
#define BH (BB*HH)
#define SCALE 0.1767766952966369f
#define S2LOG (SCALE * 1.4426950408889634f)   // scale * log2(e)

typedef __attribute__((ext_vector_type(8))) short short8;
typedef __attribute__((ext_vector_type(4))) short short4v;
typedef __attribute__((ext_vector_type(4))) float f32x4;
typedef __attribute__((ext_vector_type(4))) unsigned u32x4;
typedef __hip_bfloat16 bf16;

#define MFMA16(a,b,c) __builtin_amdgcn_mfma_f32_16x16x32_bf16(a,b,c,0,0,0)

static __device__ inline short8 ldg8(const bf16* p) {
  return *reinterpret_cast<const short8*>(p);
}
static __device__ inline short4v ldg4(const bf16* p) {
  return *reinterpret_cast<const short4v*>(p);
}
static __device__ inline short f2bs(float x) {
  bf16 h = __float2bfloat16(x);
  return *reinterpret_cast<short*>(&h);
}
// single-instruction pack: two f32 -> one u32 holding {bf16(lo), bf16(hi)}
static __device__ inline unsigned cvtpk(float lo, float hi) {
  unsigned r;
  asm("v_cvt_pk_bf16_f32 %0, %1, %2" : "=v"(r) : "v"(lo), "v"(hi));
  return r;
}
// load 8 contiguous f32 from global, convert to bf16 A/B-fragment
static __device__ inline short8 ldcvt8(const float* p) {
  f32x4 f0 = *reinterpret_cast<const f32x4*>(p);
  f32x4 f1 = *reinterpret_cast<const f32x4*>(p + 4);
  short8 r;
  #pragma unroll
  for (int i = 0; i < 4; ++i) { r[i] = f2bs(f0[i]); r[4+i] = f2bs(f1[i]); }
  return r;
}

// ---------------- Kernel 1: MFMA projections (unchanged) -------------------
__global__ __launch_bounds__(256) void proj_kernel(
    const float* __restrict__ lob, const float* __restrict__ hawkes,
    const float* __restrict__ Wp, const float* __restrict__ bp,
    const float* __restrict__ Win, const float* __restrict__ binp,
    bf16* __restrict__ qg, bf16* __restrict__ kg, bf16* __restrict__ vtg) {
  __shared__ bf16 hT[32*136];   // h tile; reused as q staging after ah read
  __shared__ bf16 sK[32*136];   // k staging
  __shared__ bf16 vT[128*40];   // v^T staging
  int tid = threadIdx.x;
  int wave = tid >> 6, lane = tid & 63;
  int lr = lane & 15, lq = lane >> 4;
  int r0 = blockIdx.x * 32;
  int b  = r0 >> 11, t0 = r0 & 2047;
  f32x4 z = {0.f,0.f,0.f,0.f};

  short8 alob[2][4], ahk[2];
  #pragma unroll
  for (int mt = 0; mt < 2; ++mt) {
    const float* lp = lob + (size_t)(r0 + mt*16 + lr)*128;
    #pragma unroll
    for (int kt = 0; kt < 4; ++kt) alob[mt][kt] = ldcvt8(lp + kt*32 + lq*8);
    ahk[mt] = ldcvt8(hawkes + (size_t)(r0 + mt*16 + lr)*32 + lq*8);
  }

  for (int nt = wave; nt < 8; nt += 4) {
    int cn = nt*16;
    short8 bfrag = ldcvt8(Wp + (size_t)(cn + lr)*32 + lq*8);
    float bias = bp[cn + lr];
    #pragma unroll
    for (int mt = 0; mt < 2; ++mt) {
      f32x4 c = MFMA16(ahk[mt], bfrag, z);
      #pragma unroll
      for (int r = 0; r < 4; ++r)
        hT[(mt*16 + lq*4 + r)*136 + cn + lr] = __float2bfloat16(c[r] + bias);
    }
  }
  __syncthreads();

  short8 ah[2][4];
  #pragma unroll
  for (int mt = 0; mt < 2; ++mt)
    #pragma unroll
    for (int kt = 0; kt < 4; ++kt)
      ah[mt][kt] = *reinterpret_cast<const short8*>(&hT[(mt*16 + lr)*136 + kt*32 + lq*8]);
  __syncthreads();   // hT free -> reuse as q staging

  for (int nt = wave; nt < 24; nt += 4) {
    int which = nt >> 3;
    int c = (nt & 7)*16 + lr;
    const float* wrow = Win + (size_t)(which*128 + c)*128;
    float bias = binp[which*128 + c];
    f32x4 acc0 = z, acc1 = z;
    #pragma unroll
    for (int kt = 0; kt < 4; ++kt) {
      short8 bfrag = ldcvt8(wrow + kt*32 + lq*8);
      if (which == 0) {
        acc0 = MFMA16(alob[0][kt], bfrag, acc0);
        acc1 = MFMA16(alob[1][kt], bfrag, acc1);
      } else {
        acc0 = MFMA16(ah[0][kt], bfrag, acc0);
        acc1 = MFMA16(ah[1][kt], bfrag, acc1);
      }
    }
    #pragma unroll
    for (int mt = 0; mt < 2; ++mt) {
      f32x4 acc = mt ? acc1 : acc0;
      #pragma unroll
      for (int r = 0; r < 4; ++r) {
        int row = mt*16 + lq*4 + r;
        float val = acc[r] + bias;
        if (which == 0)      hT[row*136 + c] = __float2bfloat16(val);
        else if (which == 1) sK[row*136 + c] = __float2bfloat16(val);
        else                 vT[c*40 + row]  = __float2bfloat16(val);
      }
    }
  }
  __syncthreads();

  // q,k writeout: 256 threads x 32B, fully contiguous 4KB per head
  {
    int head = tid >> 6, tt = (tid >> 1) & 31, half = tid & 1;
    const bf16* sq = &hT[tt*136 + head*32 + half*16];
    const bf16* sk = &sK[tt*136 + head*32 + half*16];
    bf16* qdst = qg + ((size_t)(b*HH + head)*TT + t0 + tt)*32 + half*16;
    bf16* kdst = kg + ((size_t)(b*HH + head)*TT + t0 + tt)*32 + half*16;
    *reinterpret_cast<short8*>(qdst)     = *reinterpret_cast<const short8*>(sq);
    *reinterpret_cast<short8*>(qdst + 8) = *reinterpret_cast<const short8*>(sq + 8);
    *reinterpret_cast<short8*>(kdst)     = *reinterpret_cast<const short8*>(sk);
    *reinterpret_cast<short8*>(kdst + 8) = *reinterpret_cast<const short8*>(sk + 8);
  }
  // v writeout: 128 dd-rows x 32 t, coalesced 16B stores
  {
    int dd = tid >> 1, half = tid & 1;
    int bh = b*HH + (dd >> 5);
    short8 s0 = *reinterpret_cast<const short8*>(&vT[dd*40 + half*16]);
    short8 s1 = *reinterpret_cast<const short8*>(&vT[dd*40 + half*16 + 8]);
    bf16* dst = vtg + ((size_t)bh*32 + (dd & 31))*TT + t0 + half*16;
    *reinterpret_cast<short8*>(dst) = s0;
    *reinterpret_cast<short8*>(dst + 8) = s1;
  }
}

// ------- Kernel 2: fused attention + out-proj + residual + LayerNorm -------
// 512 threads = 8 waves: wave w -> (head = w&3, half = w>>2). Half h owns
// k-chunks of parity h; each wave runs the R6/R7 prefetched pipeline over 32
// chunks (half the serial path), doubling resident waves/CU (occupancy
// 25% -> 50% theoretical) without touching the per-wave schedule.
// plds: one 4-head buffer per half (single-buffered, 2 barriers/step =
// same 64-barrier total). Denominators: cross-half LDS reduce. ctx: partials
// per half summed in LDS, then fused out-proj + residual + LN epilogue
// (8 N-tiles -> one per wave).
__global__ __launch_bounds__(512) void attn_kernel(const bf16* __restrict__ qg,
    const bf16* __restrict__ kg, const bf16* __restrict__ vtg,
    float* __restrict__ attn_out, const float* __restrict__ lobf,
    const float* __restrict__ Wo, const float* __restrict__ bo,
    const float* __restrict__ gamma, const float* __restrict__ beta,
    float* __restrict__ outg) {
  // XCD swizzle: 512 blocks = 8 XCDs x 64; each XCD owns one batch b.
  int wgid = (blockIdx.x & 7)*64 + (blockIdx.x >> 3);
  int b = wgid >> 6, qt = wgid & 63;
  int tid = threadIdx.x;
  int wave = tid >> 6, lane = tid & 63;
  int head = wave & 3, half = wave >> 2;
  int lr = lane & 15, lq = lane >> 4;
  int bh = b*HH + head;
  __shared__ float plds[2][4][32*36];   // [half][head][32x36] = 36864 B
  const bf16* qp = qg + ((size_t)bh*TT + (size_t)qt*32)*32;
  const bf16* kb = kg + (size_t)bh*TT*32;
  const bf16* vb = vtg + (size_t)bh*32*TT;
  f32x4 z = {0.f,0.f,0.f,0.f};

  // Q B-frags: lane holds Q[q=m*16+lr][d=lq*8+j]
  short8 aq0 = ldg8(qp + lr*32 + lq*8);
  short8 aq1 = ldg8(qp + (16+lr)*32 + lq*8);

  // ---- pass 1: partial denominators over this half's 32 chunks (parity half)
  float rs0 = 0.f, rs1 = 0.f;
  {
    short8 kA0 = ldg8(kb + (size_t)(half*32 + lr)*32 + lq*8);
    short8 kA1 = ldg8(kb + (size_t)(half*32 + 16 + lr)*32 + lq*8);
    short8 kB0, kB1;
#define P1STEP(KC0, KC1, KN0, KN1, NCC) { \
    int nc_ = (NCC); \
    KN0 = ldg8(kb + (size_t)(nc_*32 + lr)*32 + lq*8); \
    KN1 = ldg8(kb + (size_t)(nc_*32 + 16 + lr)*32 + lq*8); \
    f32x4 sa0 = MFMA16(KC0, aq0, z), sb0 = MFMA16(KC1, aq0, z); \
    f32x4 sa1 = MFMA16(KC0, aq1, z), sb1 = MFMA16(KC1, aq1, z); \
    _Pragma("unroll") for (int r = 0; r < 4; ++r) { \
      rs0 += exp2f(sa0[r]*S2LOG) + exp2f(sb0[r]*S2LOG); \
      rs1 += exp2f(sa1[r]*S2LOG) + exp2f(sb1[r]*S2LOG); } }
    #pragma unroll 1
    for (int i = 0; i < 32; i += 2) {
      P1STEP(kA0, kA1, kB0, kB1, 2*(i+1) + half);
      P1STEP(kB0, kB1, kA0, kA1, (i+2 < 32) ? 2*(i+2) + half : half);
    }
#undef P1STEP
  }
  rs0 += __shfl_xor(rs0, 16, 64); rs0 += __shfl_xor(rs0, 32, 64);
  rs1 += __shfl_xor(rs1, 16, 64); rs1 += __shfl_xor(rs1, 32, 64);
  // cross-half reduce via LDS (sdl aliases plds[0][0][0:256])
  float* sdl = &plds[0][0][0];
  if (lq == 0) { sdl[wave*32 + lr] = rs0; sdl[wave*32 + 16 + lr] = rs1; }
  __syncthreads();
  float lb0 = -log2f(sdl[head*32 + lr]      + sdl[(4+head)*32 + lr]);
  float lb1 = -log2f(sdl[head*32 + 16 + lr] + sdl[(4+head)*32 + 16 + lr]);
  __syncthreads();   // sdl region reused by pass-2 plds writes

  // ---- pass 2: normalized P -> attn_w mean (via plds) + PV (registers)
  f32x4 acc00 = z, acc01 = z, acc10 = z, acc11 = z;  // [m][dt], this half
  float* awr = attn_out + (size_t)(b*TT + qt*32)*TT;
  int mloc = tid & 255;
  int mq = mloc >> 3, mk = (mloc & 7)*4;   // mean mapping: 256 thr per half

  short8 kA0 = ldg8(kb + (size_t)(half*32 + lr)*32 + lq*8);
  short8 kA1 = ldg8(kb + (size_t)(half*32 + 16 + lr)*32 + lq*8);
  short4v vA00 = ldg4(vb + (size_t)lr*TT + half*32 + lq*4);
  short4v vA01 = ldg4(vb + (size_t)lr*TT + half*32 + 16 + lq*4);
  short4v vA10 = ldg4(vb + (size_t)(16+lr)*TT + half*32 + lq*4);
  short4v vA11 = ldg4(vb + (size_t)(16+lr)*TT + half*32 + 16 + lq*4);
  short8 kB0, kB1; short4v vB00, vB01, vB10, vB11;

#define P2STEP(KC, KC0, KC1, VC00, VC01, VC10, VC11, KN0, KN1, VN00, VN01, VN10, VN11, NCC) { \
    int kc_ = (KC); int nc_ = (NCC); \
    KN0 = ldg8(kb + (size_t)(nc_*32 + lr)*32 + lq*8); \
    KN1 = ldg8(kb + (size_t)(nc_*32 + 16 + lr)*32 + lq*8); \
    VN00 = ldg4(vb + (size_t)lr*TT + nc_*32 + lq*4); \
    VN01 = ldg4(vb + (size_t)lr*TT + nc_*32 + 16 + lq*4); \
    VN10 = ldg4(vb + (size_t)(16+lr)*TT + nc_*32 + lq*4); \
    VN11 = ldg4(vb + (size_t)(16+lr)*TT + nc_*32 + 16 + lq*4); \
    f32x4 s00 = MFMA16(KC0, aq0, z), s10 = MFMA16(KC1, aq0, z); \
    f32x4 s01 = MFMA16(KC0, aq1, z), s11 = MFMA16(KC1, aq1, z); \
    f32x4 p00, p10, p01, p11; \
    _Pragma("unroll") for (int r = 0; r < 4; ++r) { \
      p00[r] = exp2f(fmaf(s00[r], S2LOG, lb0)); \
      p10[r] = exp2f(fmaf(s10[r], S2LOG, lb0)); \
      p01[r] = exp2f(fmaf(s01[r], S2LOG, lb1)); \
      p11[r] = exp2f(fmaf(s11[r], S2LOG, lb1)); } \
    { float* pw = &plds[half][head][0]; \
      *reinterpret_cast<f32x4*>(pw + lr*36 + lq*4)           = p00; \
      *reinterpret_cast<f32x4*>(pw + lr*36 + 16 + lq*4)      = p10; \
      *reinterpret_cast<f32x4*>(pw + (16+lr)*36 + lq*4)      = p01; \
      *reinterpret_cast<f32x4*>(pw + (16+lr)*36 + 16 + lq*4) = p11; } \
    u32x4 ua_, ub_; \
    ua_[0] = cvtpk(p00[0], p00[1]); ua_[1] = cvtpk(p00[2], p00[3]); \
    ua_[2] = cvtpk(p10[0], p10[1]); ua_[3] = cvtpk(p10[2], p10[3]); \
    ub_[0] = cvtpk(p01[0], p01[1]); ub_[1] = cvtpk(p01[2], p01[3]); \
    ub_[2] = cvtpk(p11[0], p11[1]); ub_[3] = cvtpk(p11[2], p11[3]); \
    short8 ap0 = *reinterpret_cast<short8*>(&ua_); \
    short8 ap1 = *reinterpret_cast<short8*>(&ub_); \
    __syncthreads(); \
    { const float* pr = &plds[half][0][0]; \
      f32x4 mv = *reinterpret_cast<const f32x4*>(pr + mq*36 + mk); \
      mv = mv + *reinterpret_cast<const f32x4*>(pr + 1152 + mq*36 + mk); \
      mv = mv + *reinterpret_cast<const f32x4*>(pr + 2304 + mq*36 + mk); \
      mv = mv + *reinterpret_cast<const f32x4*>(pr + 3456 + mq*36 + mk); \
      *reinterpret_cast<f32x4*>(awr + (size_t)mq*TT + kc_*32 + mk) = mv * 0.25f; } \
    short8 vf0, vf1; \
    _Pragma("unroll") for (int j = 0; j < 4; ++j) { \
      vf0[j] = VC00[j]; vf0[4+j] = VC01[j]; \
      vf1[j] = VC10[j]; vf1[4+j] = VC11[j]; } \
    acc00 = MFMA16(ap0, vf0, acc00); acc01 = MFMA16(ap0, vf1, acc01); \
    acc10 = MFMA16(ap1, vf0, acc10); acc11 = MFMA16(ap1, vf1, acc11); \
    __syncthreads(); }

  #pragma unroll 1
  for (int i = 0; i < 32; i += 2) {
    P2STEP(2*i + half, kA0, kA1, vA00, vA01, vA10, vA11,
           kB0, kB1, vB00, vB01, vB10, vB11, 2*(i+1) + half);
    P2STEP(2*(i+1) + half, kB0, kB1, vB00, vB01, vB10, vB11,
           kA0, kA1, vA00, vA01, vA10, vA11, (i+2 < 32) ? 2*(i+2) + half : half);
  }
#undef P2STEP

  // ---- cross-half ctx reduction, then out-proj + residual + LayerNorm
  size_t rowbase = (size_t)(b*TT) + (size_t)qt*32;
  float* sRed = &plds[0][0][0];   // [half][32 x 132] = 8448 floats (of 9216)
  {
    float* myR = sRed + half*4224;
    #pragma unroll
    for (int m = 0; m < 2; ++m) {
      f32x4 a0 = m ? acc10 : acc00;
      f32x4 a1 = m ? acc11 : acc01;
      #pragma unroll
      for (int r = 0; r < 4; ++r) {
        int row = m*16 + lq*4 + r;
        myR[row*132 + head*32 + lr]      = a0[r];
        myR[row*132 + head*32 + 16 + lr] = a1[r];
      }
    }
  }
  __syncthreads();
  for (int idx = tid; idx < 4096; idx += 512) {
    int row = idx >> 7, d = idx & 127;
    sRed[row*132 + d] += sRed[4224 + row*132 + d];
  }
  __syncthreads();
  float* sX  = sRed;          // ctx (f32), 32 x 132
  float* sX2 = sRed + 4224;   // x = ctx@Wo^T + bo + lob
  // ctx A-frags from sX (f32 -> bf16 via cvt_pk); same for all waves
  short8 actx[2][4];
  #pragma unroll
  for (int mt = 0; mt < 2; ++mt)
    #pragma unroll
    for (int kt = 0; kt < 4; ++kt) {
      const float* cp = &sX[(mt*16 + lr)*132 + kt*32 + lq*8];
      f32x4 c0 = *reinterpret_cast<const f32x4*>(cp);
      f32x4 c1 = *reinterpret_cast<const f32x4*>(cp + 4);
      u32x4 u;
      u[0] = cvtpk(c0[0], c0[1]); u[1] = cvtpk(c0[2], c0[3]);
      u[2] = cvtpk(c1[0], c1[1]); u[3] = cvtpk(c1[2], c1[3]);
      actx[mt][kt] = *reinterpret_cast<short8*>(&u);
    }
  // out = ctx @ Wo^T + bo + lob -> sX2 (one N-tile per wave)
  {
    int nt = wave;
    f32x4 acc0 = z, acc1 = z;
    #pragma unroll
    for (int kt = 0; kt < 4; ++kt) {
      short8 bfrag = ldcvt8(Wo + (size_t)(nt*16 + lr)*128 + kt*32 + lq*8);
      acc0 = MFMA16(actx[0][kt], bfrag, acc0);
      acc1 = MFMA16(actx[1][kt], bfrag, acc1);
    }
    int d = nt*16 + lr;
    float bias = bo[d];
    #pragma unroll
    for (int mt = 0; mt < 2; ++mt) {
      f32x4 acc = mt ? acc1 : acc0;
      #pragma unroll
      for (int r = 0; r < 4; ++r) {
        int row = mt*16 + lq*4 + r;
        sX2[row*132 + d] = acc[r] + bias + lobf[(rowbase + row)*128 + d];
      }
    }
  }
  __syncthreads();
  // LayerNorm: 16 threads per row, 8 f32 each
  {
    int row = tid >> 4, j = tid & 15;
    const float* xp = &sX2[row*132 + j*8];
    f32x4 x0 = *reinterpret_cast<const f32x4*>(xp);
    f32x4 x1 = *reinterpret_cast<const f32x4*>(xp + 4);
    float sum = 0.f, sq = 0.f;
    #pragma unroll
    for (int e = 0; e < 4; ++e) {
      sum += x0[e] + x1[e];
      sq  += x0[e]*x0[e] + x1[e]*x1[e];
    }
    #pragma unroll
    for (int mdx = 1; mdx < 16; mdx <<= 1) {
      sum += __shfl_xor(sum, mdx, 64);
      sq  += __shfl_xor(sq,  mdx, 64);
    }
    float mu = sum * (1.0f/128.0f);
    float rstd = rsqrtf(sq*(1.0f/128.0f) - mu*mu + 1e-5f);
    float* op = outg + (rowbase + row)*128 + j*8;
    f32x4 o0, o1;
    #pragma unroll
    for (int e = 0; e < 4; ++e) {
      int d = j*8 + e;
      o0[e] = (x0[e] - mu)*rstd*gamma[d]   + beta[d];
      o1[e] = (x1[e] - mu)*rstd*gamma[d+4] + beta[d+4];
    }
    *reinterpret_cast<f32x4*>(op)     = o0;
    *reinterpret_cast<f32x4*>(op + 4) = o1;
  }
}

extern "C" void kernel_launch(void* const* d_in, const int* in_sizes, int n_in,
                              void* d_out, int out_size, void* d_ws, size_t ws_size,
                              hipStream_t stream) {
  const float* lob    = (const float*)d_in[0];
  const float* hawkes = (const float*)d_in[1];
  const float* Wp     = (const float*)d_in[2];
  const float* bp     = (const float*)d_in[3];
  const float* Win    = (const float*)d_in[4];
  const float* binp   = (const float*)d_in[5];
  const float* Wo     = (const float*)d_in[6];
  const float* bo     = (const float*)d_in[7];
  const float* gamma  = (const float*)d_in[8];
  const float* beta   = (const float*)d_in[9];
  float* outg = (float*)d_out;
  float* attn_out = outg + (size_t)BT*128;   // out (B,T,128) then attn_w (B,T,T)

  char* ws = (char*)d_ws;
  bf16*  qg   = (bf16*)(ws);                                   // 4 MB
  bf16*  kg   = (bf16*)(ws + (size_t)4*1024*1024);             // 4 MB
  bf16*  vtg  = (bf16*)(ws + (size_t)8*1024*1024);             // 4 MB (B,H,32,T)

  proj_kernel<<<BT/32, 256, 0, stream>>>(lob, hawkes, Wp, bp, Win, binp, qg, kg, vtg);
  attn_kernel<<<BB*(TT/32), 512, 0, stream>>>(qg, kg, vtg, attn_out,
                                              lob, Wo, bo, gamma, beta, outg);
}